// Round 1
// baseline (529.420 us; speedup 1.0000x reference)
//
#include <hip/hip_runtime.h>
#include <cstdint>

// Problem constants (from reference): N=8, C=3, H=720, W=1280
constexpr int N_ = 8;
constexpr int C_ = 3;
constexpr int H_ = 720;
constexpr int W_ = 1280;
constexpr int HW = H_ * W_;

// Scatter: each source pixel p computes its target and atomically maxes a
// 64-bit key = (bits(v) << 32) | (p+1). v = fx*fx+fy*fy >= 0, so IEEE bit
// pattern preserves ordering; low 32 bits implement the "larger source index
// wins ties" rule from the reference's stable ascending argsort.
__global__ void warp_scatter_kernel(const float* __restrict__ flow,
                                    unsigned long long* __restrict__ keys) {
    int idx = blockIdx.x * blockDim.x + threadIdx.x;
    if (idx >= N_ * HW) return;
    int n = idx / HW;
    int p = idx - n * HW;
    int y = p / W_;
    int x = p - y * W_;

    const float* fptr = flow + (size_t)n * 2 * HW;
    float fx = fptr[p];          // flow[n,0,y,x]
    float fy = fptr[HW + p];     // flow[n,1,y,x]

    // trunc-toward-zero, matching .astype(int32) / torch .long()
    int wx = x + (int)fx;
    int wy = y + (int)fy;
    wx = min(max(wx, 0), W_ - 1);
    wy = min(max(wy, 0), H_ - 1);
    int tgt = wy * W_ + wx;

    // exact mul-mul-add in fp32, no FMA contraction (must match JAX bits)
    float v = __fadd_rn(__fmul_rn(fx, fx), __fmul_rn(fy, fy));
    unsigned int vbits = __float_as_uint(v);
    unsigned long long key =
        ((unsigned long long)vbits << 32) | (unsigned int)(p + 1);

    atomicMax(&keys[(size_t)n * HW + tgt], key);
}

// Gather: per target pixel, decode winner and copy 3 channels (0 for holes).
__global__ void warp_gather_kernel(const float* __restrict__ image,
                                   const unsigned long long* __restrict__ keys,
                                   float* __restrict__ out) {
    int idx = blockIdx.x * blockDim.x + threadIdx.x;
    if (idx >= N_ * HW) return;
    int n = idx / HW;
    int p = idx - n * HW;

    unsigned long long key = keys[(size_t)n * HW + p];
    const float* img_n = image + (size_t)n * C_ * HW;
    float* out_n = out + (size_t)n * C_ * HW;

    if (key == 0ULL) {
        #pragma unroll
        for (int c = 0; c < C_; ++c) out_n[(size_t)c * HW + p] = 0.0f;
    } else {
        int src = (int)(unsigned int)(key & 0xffffffffULL) - 1;
        #pragma unroll
        for (int c = 0; c < C_; ++c)
            out_n[(size_t)c * HW + p] = img_n[(size_t)c * HW + src];
    }
}

extern "C" void kernel_launch(void* const* d_in, const int* in_sizes, int n_in,
                              void* d_out, int out_size, void* d_ws, size_t ws_size,
                              hipStream_t stream) {
    const float* image = (const float*)d_in[0];
    const float* flow  = (const float*)d_in[1];
    float* out = (float*)d_out;

    unsigned long long* keys = (unsigned long long*)d_ws;
    size_t keys_bytes = (size_t)N_ * HW * sizeof(unsigned long long); // ~59 MB

    hipMemsetAsync(keys, 0, keys_bytes, stream);

    int total = N_ * HW;
    int block = 256;
    int grid = (total + block - 1) / block;
    warp_scatter_kernel<<<grid, block, 0, stream>>>(flow, keys);
    warp_gather_kernel<<<grid, block, 0, stream>>>(image, keys, out);
}